// Round 12
// baseline (2546.766 us; speedup 1.0000x reference)
//
#include <hip/hip_runtime.h>
#include <math.h>

#define Bq 512
#define Tq 128
#define Fq 64
#define Uq 1024
#define OSTEPS 24
#define NKC16 68

typedef __bf16 bf16x8 __attribute__((ext_vector_type(8)));
typedef __bf16 bf16x4 __attribute__((ext_vector_type(4)));
typedef __bf16 bf16x2 __attribute__((ext_vector_type(2)));
typedef float f32x16 __attribute__((ext_vector_type(16)));
typedef float f32x4 __attribute__((ext_vector_type(4)));
typedef float f32x2 __attribute__((ext_vector_type(2)));

__device__ __forceinline__ float sigmoidf_(float x) {
    return 1.0f / (1.0f + __expf(-x));
}
__device__ __forceinline__ float tanhf_(float x) {
    return 2.0f / (1.0f + __expf(-2.0f * x)) - 1.0f;
}

// barrier WITHOUT vmcnt drain: LDS-complete + hw barrier; global loads stay in flight
#define BAR() do {                                             \
    asm volatile("s_waitcnt lgkmcnt(0)" ::: "memory");         \
    __builtin_amdgcn_s_barrier();                              \
} while (0)

// ---------------------------------------------------------------------------
// Pack Wh [1024][4096] + Wx [64][4096] (fp32, z-col = g*1024+u) into B-fragment
// order for v_mfma_f32_32x32x16_bf16, single bf16 (hi) plane. (r11-verified)
// ---------------------------------------------------------------------------
__global__ __launch_bounds__(256)
void pack_w(const float* __restrict__ Wh, const float* __restrict__ Wx,
            bf16x8* __restrict__ BpH)
{
    long id = (long)blockIdx.x * 256 + threadIdx.x;   // 128*68*64 slots
    int lane = (int)(id & 63);
    long rest = id >> 6;
    int kc16 = (int)(rest % NKC16);
    int gcol = (int)(rest / NKC16);                   // 0..127
    int col = (gcol >> 5) * Uq + (gcol & 31) * 32 + (lane & 31);
    int k0 = kc16 * 16 + (lane >> 5) * 8;
    bf16x8 hv;
#pragma unroll
    for (int j = 0; j < 8; ++j) {
        int k = k0 + j;
        float v = (k < Uq) ? Wh[(size_t)k * (4 * Uq) + col]
                           : Wx[(size_t)(k - Uq) * (4 * Uq) + col];
        hv[j] = (__bf16)v;
    }
    BpH[id] = hv;
}

// ---------------------------------------------------------------------------
// Fused LSTM step, MFMA bf16x2 split (h hi/lo x W hi). r11 structure (2351us)
// with: (a) non-temporal x/c/h-out accesses so B stays L2-resident across
// steps; (b) epilogue c + bias loads hoisted above the K-loop.
// Block: 64 rows x 32 units, 512 thr = 8 waves; wave = (gp, kq); grid 256.
// ---------------------------------------------------------------------------
#define STAGE_LOAD(c, j) do {                                                   \
    if ((c) < 16) {                                                             \
        ash[j] = *(const bf16x8*)(hrow_hi + (c) * 64);                          \
        asl[j] = *(const bf16x8*)(hrow_lo + (c) * 64);                          \
    } else {                                                                    \
        f32x4 v0_ = __builtin_nontemporal_load((const f32x4*)xrow);             \
        f32x4 v1_ = __builtin_nontemporal_load((const f32x4*)(xrow + 4));       \
        bf16x8 hv_, lv_;                                                        \
        _Pragma("unroll")                                                       \
        for (int j_ = 0; j_ < 4; ++j_) { float v = v0_[j_]; __bf16 h_ = (__bf16)v; \
            hv_[j_] = h_; lv_[j_] = (__bf16)(v - (float)h_); }                  \
        _Pragma("unroll")                                                       \
        for (int j_ = 0; j_ < 4; ++j_) { float v = v1_[j_]; __bf16 h_ = (__bf16)v; \
            hv_[4 + j_] = h_; lv_[4 + j_] = (__bf16)(v - (float)h_); }          \
        ash[j] = hv_; asl[j] = lv_;                                             \
    }                                                                           \
} while (0)

#define STAGE_WRITE(nb, j) do {                                                 \
    As2[nb][0][smh][sslot] = ash[j];                                            \
    As2[nb][1][smh][sslot] = asl[j];                                            \
} while (0)

#define LOADB(s, c) do {                                                        \
    Bh[s][0] = bpH0[((c) * 4 + kq) * 64];                                       \
    Bh[s][1] = bpH1[((c) * 4 + kq) * 64];                                       \
} while (0)

#define COMPUTE(cb, si) do {                                                    \
    bf16x8 ah0_ = As2[cb][0][0][rdslot];                                        \
    bf16x8 al0_ = As2[cb][1][0][rdslot];                                        \
    bf16x8 ah1_ = As2[cb][0][1][rdslot];                                        \
    bf16x8 al1_ = As2[cb][1][1][rdslot];                                        \
    __builtin_amdgcn_s_setprio(1);                                              \
    _Pragma("unroll")                                                           \
    for (int g2_ = 0; g2_ < 2; ++g2_) {                                         \
        acc[g2_][0] = __builtin_amdgcn_mfma_f32_32x32x16_bf16(ah0_, Bh[si][g2_], acc[g2_][0], 0, 0, 0); \
        acc[g2_][0] = __builtin_amdgcn_mfma_f32_32x32x16_bf16(al0_, Bh[si][g2_], acc[g2_][0], 0, 0, 0); \
        acc[g2_][1] = __builtin_amdgcn_mfma_f32_32x32x16_bf16(ah1_, Bh[si][g2_], acc[g2_][1], 0, 0, 0); \
        acc[g2_][1] = __builtin_amdgcn_mfma_f32_32x32x16_bf16(al1_, Bh[si][g2_], acc[g2_][1], 0, 0, 0); \
    }                                                                           \
    __builtin_amdgcn_s_setprio(0);                                              \
} while (0)

__global__ __launch_bounds__(512, 2)
void lstm_step(const __bf16* __restrict__ hhi_in,   // [512][1024]
               const __bf16* __restrict__ hlo_in,
               const float* __restrict__ xsrc,      // fp32, 64 cols, stride xstride
               long xstride,
               const bf16x8* __restrict__ BpH,
               const float* __restrict__ bias,      // [4096]
               __bf16* __restrict__ hhi_out,
               __bf16* __restrict__ hlo_out,
               float* __restrict__ c_st)            // [512][1024] fp32 in/out
{
    // union: A-staging frags (32 KB) then gate-exchange zsd (72 KB)
    __shared__ __align__(16) char smem[4 * 4 * 32 * 36 * 4];
    bf16x8 (*As2)[2][2][256] = (bf16x8 (*)[2][2][256])smem;   // [buf][plane][mh][slot]
    float (*zsd)[4][32][36] = (float (*)[4][32][36])smem;     // [kq][g][row][col]

    const int tid = threadIdx.x;
    const int l   = tid & 63;
    const int w   = tid >> 6;
    const int gp  = w & 1;          // gate pair: gates 2gp, 2gp+1
    const int kq  = w >> 1;         // K-quarter 0..3
    const int bm  = (int)blockIdx.x >> 5;
    const int bu  = (int)blockIdx.x & 31;
    const int row0 = bm * 64;

    // staging decomposition: 64 rows x 8 k-octets (r3/r5/r11-verified)
    const int srow = tid >> 3;      // 0..63
    const int kg8  = tid & 7;       // 0..7
    const int smh  = srow >> 5;
    const int sr31 = srow & 31;
    const int sslot = sr31 * 8 + (kg8 ^ (sr31 & 7));

    // fragment read slot (kc = kq), loop-invariant
    const int rdslot = (l & 31) * 8 + ((kq * 2 + (l >> 5)) ^ (l & 7));

    // per-wave global base pointers
    const bf16x8* bpH0 = BpH + ((size_t)((gp * 2 + 0) * 32 + bu) * NKC16) * 64 + l;
    const bf16x8* bpH1 = BpH + ((size_t)((gp * 2 + 1) * 32 + bu) * NKC16) * 64 + l;
    const __bf16* hrow_hi = hhi_in + (size_t)(row0 + srow) * Uq + kg8 * 8;
    const __bf16* hrow_lo = hlo_in + (size_t)(row0 + srow) * Uq + kg8 * 8;
    const float*  xrow    = xsrc + (size_t)(row0 + srow) * xstride + kg8 * 8;

    // ---- hoisted epilogue state: c (non-temporal) + bias, latency hidden ----
    const int erow = tid >> 4;          // 0..31
    const int euu  = (tid & 15) * 2;    // 0..30
    const int egu  = bu * 32 + euu;
    const size_t gidx0 = (size_t)(row0 + erow) * Uq + egu;
    const size_t gidx1 = gidx0 + (size_t)32 * Uq;
    f32x2 cvp[2];
    cvp[0] = __builtin_nontemporal_load((const f32x2*)(c_st + gidx0));
    cvp[1] = __builtin_nontemporal_load((const f32x2*)(c_st + gidx1));
    const f32x2 bi  = *(const f32x2*)(bias + 0 * Uq + egu);
    const f32x2 bf2 = *(const f32x2*)(bias + 1 * Uq + egu);
    const f32x2 bg2 = *(const f32x2*)(bias + 2 * Uq + egu);
    const f32x2 bo2 = *(const f32x2*)(bias + 3 * Uq + egu);

    f32x16 acc[2][2];
#pragma unroll
    for (int i = 0; i < 16; ++i) {
        acc[0][0][i] = 0.0f; acc[0][1][i] = 0.0f;
        acc[1][0][i] = 0.0f; acc[1][1][i] = 0.0f;
    }

    bf16x8 Bh[3][2];
    bf16x8 ash[2], asl[2];

    // ---- prologue ----
    STAGE_LOAD(0, 0);
    STAGE_LOAD(1, 1);
    LOADB(0, 0);
    LOADB(1, 1);
    STAGE_WRITE(0, 0);
    BAR();

    // ---- fully-unrolled pipelined K loop: 17 chunks ----
#pragma unroll
    for (int i = 0; i < 17; ++i) {
        if (i <= 14) {
            LOADB((i + 2) % 3, i + 2);
            STAGE_LOAD(i + 2, i & 1);        // (i+2)&1 == i&1
        }
        if (i <= 15) STAGE_WRITE((i + 1) & 1, (i + 1) & 1);
        COMPUTE(i & 1, i % 3);
        if (i < 16) BAR();
    }

    BAR();   // all fragment reads retired; smem becomes zsd

    // ---- epilogue: two passes over M-halves ----
#pragma unroll
    for (int mh = 0; mh < 2; ++mh) {
        // write partials: zsd[kq][gate][row][unit]
#pragma unroll
        for (int g2 = 0; g2 < 2; ++g2)
#pragma unroll
            for (int r = 0; r < 16; ++r) {
                int rowi = (r & 3) + 8 * (r >> 2) + 4 * (l >> 5);
                zsd[kq][gp * 2 + g2][rowi][l & 31] = acc[g2][mh][r];
            }
        BAR();
        // reduce 4 K-quarters + gates + state update (32 rows x 32 units)
        {
            const size_t gidx = (mh == 0) ? gidx0 : gidx1;
            float z[4][2];
#pragma unroll
            for (int g = 0; g < 4; ++g) {
#pragma unroll
                for (int j = 0; j < 2; ++j)
                    z[g][j] = zsd[0][g][erow][euu + j] + zsd[1][g][erow][euu + j]
                            + zsd[2][g][erow][euu + j] + zsd[3][g][erow][euu + j];
            }
            f32x2 cv = cvp[mh];
            bf16x2 hh, hl2;
#pragma unroll
            for (int j = 0; j < 2; ++j) {
                float vi = sigmoidf_(z[0][j] + bi[j]);
                float vf = sigmoidf_(z[1][j] + bf2[j]);
                float vg = tanhf_  (z[2][j] + bg2[j]);
                float vo = sigmoidf_(z[3][j] + bo2[j]);
                float cn = vf * cv[j] + vi * vg;
                cv[j] = cn;
                float hval = vo * tanhf_(cn);
                __bf16 h_ = (__bf16)hval;
                hh[j] = h_;
                hl2[j] = (__bf16)(hval - (float)h_);
            }
            __builtin_nontemporal_store(cv, (f32x2*)(c_st + gidx));
            __builtin_nontemporal_store(hh, (bf16x2*)(hhi_out + gidx));
            __builtin_nontemporal_store(hl2, (bf16x2*)(hlo_out + gidx));
        }
        if (mh == 0) BAR();   // pass-1 reads done before pass-2 overwrites zsd
    }
}

// ---------------------------------------------------------------------------
// Dense readout p = (hhi+hlo) @ Wd + bd ; scatter into out[:, step, :].
// (r5/r11-verified)
// ---------------------------------------------------------------------------
__global__ __launch_bounds__(256)
void readout(const __bf16* __restrict__ hhi, const __bf16* __restrict__ hlo,
             const float* __restrict__ Wd, const float* __restrict__ bd,
             float* __restrict__ p, float* __restrict__ out, int step)
{
    __shared__ float red[2][4][64];
    const int t = threadIdx.x;
    const int f = t & 63, kq = t >> 6;
    const int r0 = blockIdx.x * 2;
    float s0 = 0.0f, s1 = 0.0f;
    const __bf16* h0h = hhi + (size_t)r0 * Uq + kq * 256;
    const __bf16* h0l = hlo + (size_t)r0 * Uq + kq * 256;
    const float* wp = Wd + (size_t)kq * 256 * Fq + f;
#pragma unroll 4
    for (int i = 0; i < 32; ++i) {
        bf16x8 ah = *(const bf16x8*)(h0h + i * 8);
        bf16x8 al = *(const bf16x8*)(h0l + i * 8);
        bf16x8 bh = *(const bf16x8*)(h0h + Uq + i * 8);
        bf16x8 bl = *(const bf16x8*)(h0l + Uq + i * 8);
#pragma unroll
        for (int j = 0; j < 8; ++j) {
            float wv = wp[(size_t)(i * 8 + j) * Fq];
            s0 = fmaf((float)ah[j] + (float)al[j], wv, s0);
            s1 = fmaf((float)bh[j] + (float)bl[j], wv, s1);
        }
    }
    red[0][kq][f] = s0;
    red[1][kq][f] = s1;
    __syncthreads();
    if (t < 128) {
        int rr = t >> 6, ff = t & 63;
        float s = red[rr][0][ff] + red[rr][1][ff] + red[rr][2][ff] + red[rr][3][ff] + bd[ff];
        p[(size_t)(r0 + rr) * Fq + ff] = s;
        out[((size_t)(r0 + rr) * OSTEPS + step) * Fq + ff] = s;
    }
}

__global__ void zero_ws(f32x4* __restrict__ a, int n) {
    int i = blockIdx.x * 256 + threadIdx.x;
    f32x4 z = {0.0f, 0.0f, 0.0f, 0.0f};
    if (i < n) a[i] = z;
}

extern "C" void kernel_launch(void* const* d_in, const int* in_sizes, int n_in,
                              void* d_out, int out_size, void* d_ws, size_t ws_size,
                              hipStream_t stream) {
    const float* inputs = (const float*)d_in[0];  // [512][128][64]
    const float* Wx     = (const float*)d_in[1];  // [64][4096]
    const float* Wh     = (const float*)d_in[2];  // [1024][4096]
    const float* b      = (const float*)d_in[3];  // [4096]
    const float* Wd     = (const float*)d_in[4];  // [1024][64]
    const float* bd     = (const float*)d_in[5];  // [64]
    float* out = (float*)d_out;

    // workspace layout: c | Hhi0 | Hlo0 | Hhi1 | Hlo1 | p | BpH  (~15.2 MB)
    float* ws = (float*)d_ws;
    float* c_st = ws;                              // 512*1024 f32 (2 MB)
    __bf16* Hhi0 = (__bf16*)(ws + Bq * Uq);        // 1 MB each
    __bf16* Hlo0 = Hhi0 + Bq * Uq;
    __bf16* Hhi1 = Hlo0 + Bq * Uq;
    __bf16* Hlo1 = Hhi1 + Bq * Uq;
    float* p = (float*)(Hlo1 + Bq * Uq);           // 512*64 f32
    bf16x8* BpH = (bf16x8*)(p + Bq * Fq);          // 557056 * 16 B = 8.9 MB

    pack_w<<<2176, 256, 0, stream>>>(Wh, Wx, BpH);
    // zero c + Hhi0 + Hlo0 (contiguous 4 MB)
    zero_ws<<<1024, 256, 0, stream>>>((f32x4*)ws, 262144);

    __bf16 *hhi_c = Hhi0, *hlo_c = Hlo0, *hhi_n = Hhi1, *hlo_n = Hlo1;
    // ---- warmup over T timesteps ----
    for (int t = 0; t < Tq; ++t) {
        lstm_step<<<256, 512, 0, stream>>>(hhi_c, hlo_c,
                                           inputs + (size_t)t * Fq, (long)Tq * Fq,
                                           BpH, b, hhi_n, hlo_n, c_st);
        __bf16* tmp;
        tmp = hhi_c; hhi_c = hhi_n; hhi_n = tmp;
        tmp = hlo_c; hlo_c = hlo_n; hlo_n = tmp;
    }
    readout<<<Bq / 2, 256, 0, stream>>>(hhi_c, hlo_c, Wd, bd, p, out, 0);
    // ---- autoregressive decode ----
    for (int s = 1; s < OSTEPS; ++s) {
        lstm_step<<<256, 512, 0, stream>>>(hhi_c, hlo_c, p, (long)Fq,
                                           BpH, b, hhi_n, hlo_n, c_st);
        __bf16* tmp;
        tmp = hhi_c; hhi_c = hhi_n; hhi_n = tmp;
        tmp = hlo_c; hlo_c = hlo_n; hlo_n = tmp;
        readout<<<Bq / 2, 256, 0, stream>>>(hhi_c, hlo_c, Wd, bd, p, out, s);
    }
}

// Round 13
// 1753.593 us; speedup vs baseline: 1.4523x; 1.4523x over previous
//
#include <hip/hip_runtime.h>
#include <math.h>

#define Bq 512
#define Tq 128
#define Fq 64
#define Uq 1024
#define OSTEPS 24
#define NKC16 68

typedef _Float16 f16x8 __attribute__((ext_vector_type(8)));
typedef _Float16 f16x4 __attribute__((ext_vector_type(4)));
typedef _Float16 f16x2 __attribute__((ext_vector_type(2)));
typedef float f32x16 __attribute__((ext_vector_type(16)));
typedef float f32x4 __attribute__((ext_vector_type(4)));
typedef float f32x2 __attribute__((ext_vector_type(2)));

__device__ __forceinline__ float sigmoidf_(float x) {
    return 1.0f / (1.0f + __expf(-x));
}
__device__ __forceinline__ float tanhf_(float x) {
    return 2.0f / (1.0f + __expf(-2.0f * x)) - 1.0f;
}

// barrier WITHOUT vmcnt drain: LDS-complete + hw barrier; global loads stay in flight
#define BAR() do {                                             \
    asm volatile("s_waitcnt lgkmcnt(0)" ::: "memory");         \
    __builtin_amdgcn_s_barrier();                              \
} while (0)

// ---------------------------------------------------------------------------
// Pack Wh [1024][4096] + Wx [64][4096] (fp32, z-col = g*1024+u) into B-fragment
// order for v_mfma_f32_32x32x16_f16, single f16 plane.
// Bp[(gcol32*68 + kc16)*64 + lane]: gcol32 = g*32 + ublk; col = lane&31;
// k = kc16*16 + (lane>>5)*8 + j  (k<1024 -> Wh; else Wx row k-1024)
// ---------------------------------------------------------------------------
__global__ __launch_bounds__(256)
void pack_w(const float* __restrict__ Wh, const float* __restrict__ Wx,
            f16x8* __restrict__ BpH)
{
    long id = (long)blockIdx.x * 256 + threadIdx.x;   // 128*68*64 slots
    int lane = (int)(id & 63);
    long rest = id >> 6;
    int kc16 = (int)(rest % NKC16);
    int gcol = (int)(rest / NKC16);                   // 0..127
    int col = (gcol >> 5) * Uq + (gcol & 31) * 32 + (lane & 31);
    int k0 = kc16 * 16 + (lane >> 5) * 8;
    f16x8 hv;
#pragma unroll
    for (int j = 0; j < 8; ++j) {
        int k = k0 + j;
        float v = (k < Uq) ? Wh[(size_t)k * (4 * Uq) + col]
                           : Wx[(size_t)(k - Uq) * (4 * Uq) + col];
        hv[j] = (_Float16)v;
    }
    BpH[id] = hv;
}

// ---------------------------------------------------------------------------
// Fused LSTM step, FP16 MFMA (h bounded in (-1,1): f16 rel 2^-11 beats bf16).
// r11 structure (17-chunk unrolled pipeline, depth-2 prefetch, lgkm-only
// barriers), single A plane, 4 MFMA/chunk/wave.
// Block: 64 rows x 32 units, 512 thr = 8 waves; wave = (gp, kq); grid 256.
// ---------------------------------------------------------------------------
#define STAGE_LOAD(c, j) do {                                                   \
    if ((c) < 16) {                                                             \
        ash[j] = *(const f16x8*)(hrow + (c) * 64);                              \
    } else {                                                                    \
        f32x4 v0_ = *(const f32x4*)xrow;                                        \
        f32x4 v1_ = *(const f32x4*)(xrow + 4);                                  \
        f16x8 hv_;                                                              \
        _Pragma("unroll")                                                       \
        for (int j_ = 0; j_ < 4; ++j_) {                                        \
            hv_[j_]     = (_Float16)v0_[j_];                                    \
            hv_[4 + j_] = (_Float16)v1_[j_];                                    \
        }                                                                       \
        ash[j] = hv_;                                                           \
    }                                                                           \
} while (0)

#define STAGE_WRITE(nb, j) do {                                                 \
    As2[nb][smh][sslot] = ash[j];                                               \
} while (0)

#define LOADB(s, c) do {                                                        \
    Bh[s][0] = bpH0[((c) * 4 + kq) * 64];                                       \
    Bh[s][1] = bpH1[((c) * 4 + kq) * 64];                                       \
} while (0)

#define COMPUTE(cb, si) do {                                                    \
    f16x8 ah0_ = As2[cb][0][rdslot];                                            \
    f16x8 ah1_ = As2[cb][1][rdslot];                                            \
    __builtin_amdgcn_s_setprio(1);                                              \
    _Pragma("unroll")                                                           \
    for (int g2_ = 0; g2_ < 2; ++g2_) {                                         \
        acc[g2_][0] = __builtin_amdgcn_mfma_f32_32x32x16_f16(ah0_, Bh[si][g2_], acc[g2_][0], 0, 0, 0); \
        acc[g2_][1] = __builtin_amdgcn_mfma_f32_32x32x16_f16(ah1_, Bh[si][g2_], acc[g2_][1], 0, 0, 0); \
    }                                                                           \
    __builtin_amdgcn_s_setprio(0);                                              \
} while (0)

__global__ __launch_bounds__(512, 2)
void lstm_step(const _Float16* __restrict__ h_in,   // [512][1024] f16
               const float* __restrict__ xsrc,      // fp32, 64 cols, stride xstride
               long xstride,
               const f16x8* __restrict__ BpH,
               const float* __restrict__ bias,      // [4096]
               _Float16* __restrict__ h_out,        // [512][1024] f16
               float* __restrict__ c_st)            // [512][1024] fp32 in/out
{
    // union: A-staging frags (16 KB) then gate-exchange zsd (72 KB)
    __shared__ __align__(16) char smem[4 * 4 * 32 * 36 * 4];
    f16x8 (*As2)[2][256] = (f16x8 (*)[2][256])smem;           // [buf][mh][slot]
    float (*zsd)[4][32][36] = (float (*)[4][32][36])smem;     // [kq][g][row][col]

    const int tid = threadIdx.x;
    const int l   = tid & 63;
    const int w   = tid >> 6;
    const int gp  = w & 1;          // gate pair: gates 2gp, 2gp+1
    const int kq  = w >> 1;         // K-quarter 0..3
    const int bm  = (int)blockIdx.x >> 5;
    const int bu  = (int)blockIdx.x & 31;
    const int row0 = bm * 64;

    // staging decomposition: 64 rows x 8 k-octets (r3/r5/r11-verified)
    const int srow = tid >> 3;      // 0..63
    const int kg8  = tid & 7;       // 0..7
    const int smh  = srow >> 5;
    const int sr31 = srow & 31;
    const int sslot = sr31 * 8 + (kg8 ^ (sr31 & 7));

    // fragment read slot (kc = kq), loop-invariant
    const int rdslot = (l & 31) * 8 + ((kq * 2 + (l >> 5)) ^ (l & 7));

    // per-wave global base pointers
    const f16x8* bpH0 = BpH + ((size_t)((gp * 2 + 0) * 32 + bu) * NKC16) * 64 + l;
    const f16x8* bpH1 = BpH + ((size_t)((gp * 2 + 1) * 32 + bu) * NKC16) * 64 + l;
    const _Float16* hrow = h_in + (size_t)(row0 + srow) * Uq + kg8 * 8;
    const float*    xrow = xsrc + (size_t)(row0 + srow) * xstride + kg8 * 8;

    f32x16 acc[2][2];
#pragma unroll
    for (int i = 0; i < 16; ++i) {
        acc[0][0][i] = 0.0f; acc[0][1][i] = 0.0f;
        acc[1][0][i] = 0.0f; acc[1][1][i] = 0.0f;
    }

    f16x8 Bh[3][2];
    f16x8 ash[2];

    // ---- prologue ----
    STAGE_LOAD(0, 0);
    STAGE_LOAD(1, 1);
    LOADB(0, 0);
    LOADB(1, 1);
    STAGE_WRITE(0, 0);
    BAR();

    // ---- fully-unrolled pipelined K loop: 17 chunks ----
#pragma unroll
    for (int i = 0; i < 17; ++i) {
        if (i <= 14) {
            LOADB((i + 2) % 3, i + 2);
            STAGE_LOAD(i + 2, i & 1);        // (i+2)&1 == i&1
        }
        if (i <= 15) STAGE_WRITE((i + 1) & 1, (i + 1) & 1);
        COMPUTE(i & 1, i % 3);
        if (i < 16) BAR();
    }

    BAR();   // all fragment reads retired; smem becomes zsd

    // ---- epilogue: two passes over M-halves ----
#pragma unroll
    for (int mh = 0; mh < 2; ++mh) {
        // write partials: zsd[kq][gate][row][unit]
#pragma unroll
        for (int g2 = 0; g2 < 2; ++g2)
#pragma unroll
            for (int r = 0; r < 16; ++r) {
                int rowi = (r & 3) + 8 * (r >> 2) + 4 * (l >> 5);
                zsd[kq][gp * 2 + g2][rowi][l & 31] = acc[g2][mh][r];
            }
        BAR();
        // reduce 4 K-quarters + gates + state update (32 rows x 32 units)
        {
            const int row = tid >> 4;          // 0..31
            const int uu  = (tid & 15) * 2;    // 0..30
            const int grow = row0 + mh * 32 + row;
            const int gu   = bu * 32 + uu;
            const size_t gidx = (size_t)grow * Uq + gu;
            float z[4][2];
#pragma unroll
            for (int g = 0; g < 4; ++g) {
#pragma unroll
                for (int j = 0; j < 2; ++j)
                    z[g][j] = zsd[0][g][row][uu + j] + zsd[1][g][row][uu + j]
                            + zsd[2][g][row][uu + j] + zsd[3][g][row][uu + j];
            }
            f32x2 cv = *(const f32x2*)(c_st + gidx);
            f16x2 hh;
#pragma unroll
            for (int j = 0; j < 2; ++j) {
                float vi = sigmoidf_(z[0][j] + bias[0 * Uq + gu + j]);
                float vf = sigmoidf_(z[1][j] + bias[1 * Uq + gu + j]);
                float vg = tanhf_  (z[2][j] + bias[2 * Uq + gu + j]);
                float vo = sigmoidf_(z[3][j] + bias[3 * Uq + gu + j]);
                float cn = vf * cv[j] + vi * vg;
                cv[j] = cn;
                hh[j] = (_Float16)(vo * tanhf_(cn));
            }
            *(f32x2*)(c_st + gidx) = cv;
            *(f16x2*)(h_out + gidx) = hh;
        }
        if (mh == 0) BAR();   // pass-1 reads done before pass-2 overwrites zsd
    }
}

// ---------------------------------------------------------------------------
// Dense readout p = h @ Wd + bd ; scatter into out[:, step, :].
// ---------------------------------------------------------------------------
__global__ __launch_bounds__(256)
void readout(const _Float16* __restrict__ h, const float* __restrict__ Wd,
             const float* __restrict__ bd, float* __restrict__ p,
             float* __restrict__ out, int step)
{
    __shared__ float red[2][4][64];
    const int t = threadIdx.x;
    const int f = t & 63, kq = t >> 6;
    const int r0 = blockIdx.x * 2;
    float s0 = 0.0f, s1 = 0.0f;
    const _Float16* h0 = h + (size_t)r0 * Uq + kq * 256;
    const float* wp = Wd + (size_t)kq * 256 * Fq + f;
#pragma unroll 4
    for (int i = 0; i < 32; ++i) {
        f16x8 ah = *(const f16x8*)(h0 + i * 8);
        f16x8 bh = *(const f16x8*)(h0 + Uq + i * 8);
#pragma unroll
        for (int j = 0; j < 8; ++j) {
            float wv = wp[(size_t)(i * 8 + j) * Fq];
            s0 = fmaf((float)ah[j], wv, s0);
            s1 = fmaf((float)bh[j], wv, s1);
        }
    }
    red[0][kq][f] = s0;
    red[1][kq][f] = s1;
    __syncthreads();
    if (t < 128) {
        int rr = t >> 6, ff = t & 63;
        float s = red[rr][0][ff] + red[rr][1][ff] + red[rr][2][ff] + red[rr][3][ff] + bd[ff];
        p[(size_t)(r0 + rr) * Fq + ff] = s;
        out[((size_t)(r0 + rr) * OSTEPS + step) * Fq + ff] = s;
    }
}

__global__ void zero_ws(f32x4* __restrict__ a, int n) {
    int i = blockIdx.x * 256 + threadIdx.x;
    f32x4 z = {0.0f, 0.0f, 0.0f, 0.0f};
    if (i < n) a[i] = z;
}

extern "C" void kernel_launch(void* const* d_in, const int* in_sizes, int n_in,
                              void* d_out, int out_size, void* d_ws, size_t ws_size,
                              hipStream_t stream) {
    const float* inputs = (const float*)d_in[0];  // [512][128][64]
    const float* Wx     = (const float*)d_in[1];  // [64][4096]
    const float* Wh     = (const float*)d_in[2];  // [1024][4096]
    const float* b      = (const float*)d_in[3];  // [4096]
    const float* Wd     = (const float*)d_in[4];  // [1024][64]
    const float* bd     = (const float*)d_in[5];  // [64]
    float* out = (float*)d_out;

    // workspace layout: c (2MB) | H0 (1MB) | H1 (1MB) | p (128KB) | BpH (8.9MB)
    float* ws = (float*)d_ws;
    float* c_st = ws;                              // 512*1024 f32
    _Float16* H0 = (_Float16*)(ws + Bq * Uq);
    _Float16* H1 = H0 + Bq * Uq;
    float* p = (float*)(H1 + Bq * Uq);             // 512*64 f32
    f16x8* BpH = (f16x8*)(p + Bq * Fq);            // 557056 * 16 B = 8.9 MB

    pack_w<<<2176, 256, 0, stream>>>(Wh, Wx, BpH);
    // zero c (2MB) + H0 (1MB), contiguous 3 MB
    zero_ws<<<768, 256, 0, stream>>>((f32x4*)ws, 196608);

    _Float16 *h_c = H0, *h_n = H1;
    // ---- warmup over T timesteps ----
    for (int t = 0; t < Tq; ++t) {
        lstm_step<<<256, 512, 0, stream>>>(h_c, inputs + (size_t)t * Fq, (long)Tq * Fq,
                                           BpH, b, h_n, c_st);
        _Float16* tmp = h_c; h_c = h_n; h_n = tmp;
    }
    readout<<<Bq / 2, 256, 0, stream>>>(h_c, Wd, bd, p, out, 0);
    // ---- autoregressive decode ----
    for (int s = 1; s < OSTEPS; ++s) {
        lstm_step<<<256, 512, 0, stream>>>(h_c, p, (long)Fq, BpH, b, h_n, c_st);
        _Float16* tmp = h_c; h_c = h_n; h_n = tmp;
        readout<<<Bq / 2, 256, 0, stream>>>(h_c, Wd, bd, p, out, s);
    }
}